// Round 8
// baseline (255.745 us; speedup 1.0000x reference)
//
#include <hip/hip_runtime.h>

#define N_ 2048

typedef __attribute__((ext_vector_type(8))) __bf16 bf16x8;
typedef __attribute__((ext_vector_type(8))) unsigned short u16x8;
typedef __attribute__((ext_vector_type(4))) unsigned short u16x4;
typedef __attribute__((ext_vector_type(4))) float f32x4;

__device__ inline unsigned short f2bf(float f) {
  return __builtin_bit_cast(unsigned short, static_cast<__bf16>(f));
}
__device__ inline float bf2f(unsigned short s) {
  unsigned u = ((unsigned)s) << 16;
  return __builtin_bit_cast(float, u);
}

__device__ inline f32x4 mfma_bf16(u16x8 a, u16x8 b, f32x4 c) {
  return __builtin_amdgcn_mfma_f32_16x16x32_bf16(
      __builtin_bit_cast(bf16x8, a), __builtin_bit_cast(bf16x8, b), c, 0, 0, 0);
}

// async global->LDS, 16B per lane, linear LDS dest (wave-uniform base + lane*16)
__device__ __forceinline__ void gl_lds16(const unsigned short* g, unsigned short* l) {
  __builtin_amdgcn_global_load_lds(
      (const __attribute__((address_space(1))) unsigned int*)g,
      (__attribute__((address_space(3))) unsigned int*)l, 16, 0, 0);
}

// ---------------- prep: pack weights to bf16 ----------------
__global__ __launch_bounds__(256) void prep_weights(
    const float* __restrict__ w0, const float* __restrict__ w1,
    const float* __restrict__ Wf,
    unsigned short* __restrict__ Wc1, unsigned short* __restrict__ Wc2,
    unsigned short* __restrict__ Wcat)
{
  int idx = blockIdx.x * 256 + threadIdx.x;
  if (idx < 65536) {
    int h = idx >> 14, r = (idx >> 7) & 127, k = idx & 127;
    float v = (r < 64) ? w0[(h * 64 + r) * 128 + k]
                       : w1[(h * 64 + (r - 64)) * 192 + k];
    Wc1[idx] = f2bf(v);
  } else if (idx < 81920) {
    int i = idx - 65536;
    int h = i >> 12, r = (i >> 6) & 63, k = i & 63;
    Wc2[i] = f2bf(w1[(h * 64 + r) * 192 + 128 + k]);
  } else if (idx < 163840) {
    int i = idx - 81920;
    int d = i / 640, c = i % 640;
    float v;
    if (c < 256)      { int h = c >> 6, j = c & 63;        v = Wf[d * 512 + h * 128 + j]; }
    else if (c < 512) { int h = (c - 256) >> 6, j = (c - 256) & 63; v = Wf[d * 512 + h * 128 + 64 + j]; }
    else {
      int k = c - 512; v = 0.f;
      for (int hh = 0; hh < 4; ++hh) v += Wf[d * 512 + hh * 128 + k];
    }
    Wcat[i] = f2bf(v);
  }
}

// ---------------- prep: X -> XbT (bf16 transpose [B][128][N]) + G X-slice ----------------
__global__ __launch_bounds__(256) void prep_x(
    const float* __restrict__ X, unsigned short* __restrict__ XbT,
    unsigned short* __restrict__ G)
{
  const int tid = threadIdx.x;
  const int b = blockIdx.x >> 5;
  const int n0 = (blockIdx.x & 31) * 64;
  __shared__ float tf[64][129];
  #pragma unroll
  for (int i = 0; i < 32; ++i) {
    int e = i * 256 + tid;          // 64x128 tile
    int nl = e >> 7, c = e & 127;
    float v = X[((size_t)b * N_ + n0 + nl) * 128 + c];
    tf[nl][c] = v;
    G[((size_t)b * N_ + n0 + nl) * 640 + 512 + c] = f2bf(v);
  }
  __syncthreads();
  #pragma unroll
  for (int i = 0; i < 32; ++i) {
    int e = i * 256 + tid;
    int c = e >> 6, nl = e & 63;
    XbT[((size_t)b * 128 + c) * N_ + n0 + nl] = f2bf(tf[nl][c]);
  }
}

// ---------------- conv_adj: adj fp32 -> adjb bf16, row-sums -> dnm ----------------
// 1 wave per row; pure streaming.
__global__ __launch_bounds__(256) void conv_adj(
    const float* __restrict__ adj, unsigned short* __restrict__ adjb,
    float* __restrict__ dnm)
{
  const int tid = threadIdx.x, lane = tid & 63, w = tid >> 6;
  const int gid = blockIdx.x * 4 + w;          // row over 16*2048
  const int bh = gid >> 11, r = gid & 2047;
  const float* src = adj + (size_t)gid * N_;
  unsigned short* dst = adjb + (size_t)gid * N_;
  float s = 0.f;
  #pragma unroll
  for (int j = 0; j < 8; ++j) {
    float4 v = *(const float4*)(src + j * 256 + lane * 4);
    s += (v.x + v.y) + (v.z + v.w);
    u16x4 o;
    o[0] = f2bf(v.x); o[1] = f2bf(v.y); o[2] = f2bf(v.z); o[3] = f2bf(v.w);
    *(u16x4*)(dst + j * 256 + lane * 4) = o;
  }
  s += __shfl_xor(s, 1, 64);
  s += __shfl_xor(s, 2, 64);
  s += __shfl_xor(s, 4, 64);
  s += __shfl_xor(s, 8, 64);
  s += __shfl_xor(s, 16, 64);
  s += __shfl_xor(s, 32, 64);
  if (lane == 0) {
    const int hb = (bh & 3) * 4 + (bh >> 2);
    dnm[(size_t)hb * N_ + r] = s + 1.0f;
  }
}

// ---------------- pass1: Z0 = adjb@X + X (bf16) ----------------
// 32 rows x 128 cols per block, 4 waves 2x2. K chunks of 128.
// A (adjb) and B (XbT) both staged via gl_lds, double-buffered, XOR-swizzled.
__global__ __launch_bounds__(256, 2) void pass1_kernel(
    const unsigned short* __restrict__ adjb, const float* __restrict__ X,
    const unsigned short* __restrict__ XbT,
    unsigned short* __restrict__ Z0b)
{
  const int tid = threadIdx.x, lane = tid & 63, w = tid >> 6;
  const int wr = w >> 1, wc = w & 1;
  const int rl = lane & 15, q = lane >> 4;
  const int bh = blockIdx.y, b = bh >> 2, h = bh & 3, hb = h * 4 + b;
  const int row0 = blockIdx.x * 32;

  __shared__ __align__(16) unsigned short At[2][32 * 128];    // 2 x 8 KB
  __shared__ __align__(16) unsigned short Bt[2][128 * 128];   // 2 x 32 KB

  // staging source precompute: swizzled col bytes (shared by A and B)
  const int r4 = lane >> 4;
  const int cb = (lane & 15) * 16;
  const int e0 = (cb ^ (r4 << 4)) >> 1;          // elements, call i even
  const int e1 = (cb ^ ((4 + r4) << 4)) >> 1;    // elements, call i odd
  const unsigned short* xb = XbT + (size_t)b * 128 * N_;
  const unsigned short* ab = adjb + ((size_t)bh * N_ + row0) * N_;

  const int swz = (rl & 7) << 4;
  const int ra = wr * 16 + rl;                    // A row this lane reads
  const int raswz = (ra & 7) << 4;

  f32x4 acc[4] = {};

  auto stage = [&](int buf, int kb) {
    #pragma unroll
    for (int i = 0; i < 2; ++i) {   // A: rows w*8 + i*4 + r4
      const int R0 = w * 8 + i * 4;
      gl_lds16(ab + (size_t)(R0 + r4) * N_ + kb * 128 + ((i & 1) ? e1 : e0),
               &At[buf][R0 * 128]);
    }
    #pragma unroll
    for (int i = 0; i < 8; ++i) {   // B: rows w*32 + i*4 + r4
      const int R0 = w * 32 + i * 4;
      gl_lds16(xb + (size_t)(R0 + r4) * N_ + kb * 128 + ((i & 1) ? e1 : e0),
               &Bt[buf][R0 * 128]);
    }
  };

  stage(0, 0);
  __syncthreads();

  for (int kb = 0; kb < 16; ++kb) {
    const int cur = kb & 1;
    if (kb < 15) stage(cur ^ 1, kb + 1);   // in flight through compute
    #pragma unroll
    for (int ks = 0; ks < 4; ++ks) {
      u16x8 aF = *(const u16x8*)((const char*)&At[cur][0] + ra * 256 +
                                 ((ks * 64 + q * 16) ^ raswz));
      #pragma unroll
      for (int ct = 0; ct < 4; ++ct) {
        const int R = wc * 64 + ct * 16 + rl;
        u16x8 bF = *(const u16x8*)((const char*)&Bt[cur][0] + R * 256 +
                                   ((ks * 64 + q * 16) ^ swz));
        acc[ct] = mfma_bf16(aF, bF, acc[ct]);
      }
    }
    __syncthreads();   // readers done; vmcnt(0) -> stage(kb+1) done
  }

  #pragma unroll
  for (int j = 0; j < 4; ++j) {
    const int n = row0 + wr * 16 + q * 4 + j;
    const float* xr = X + ((size_t)b * N_ + n) * 128;
    unsigned short* zr = Z0b + ((size_t)hb * N_ + n) * 128;
    #pragma unroll
    for (int ct = 0; ct < 4; ++ct) {
      const int c = wc * 64 + ct * 16 + rl;
      zr[c] = f2bf(acc[ct][j] + xr[c]);
    }
  }
}

// ---------------- mid: g0, h0 = g0@w1b^T, e = Z0@w1a^T + h0 + 2*b1 ----------------
__global__ __launch_bounds__(256) void mid_kernel(
    const unsigned short* __restrict__ Z0b, const float* __restrict__ dnm,
    const unsigned short* __restrict__ Wc1, const unsigned short* __restrict__ Wc2,
    const float* __restrict__ bias0, const float* __restrict__ bias1,
    unsigned short* __restrict__ e_b, unsigned short* __restrict__ h0T,
    unsigned short* __restrict__ G)
{
  const int tid = threadIdx.x, lane = tid & 63, w = tid >> 6;
  const int rl = lane & 15, q = lane >> 4;
  const int h = blockIdx.y;
  const int rowbase = blockIdx.x * 64;      // over B*N = 8192
  const int b = rowbase >> 11, n0 = rowbase & 2047;
  const int r0 = rowbase + w * 16;

  __shared__ unsigned short g0s[4][16][72];
  __shared__ unsigned short h0s[4][16][72];

  const unsigned short* zb = Z0b + ((size_t)h * 8192 + r0 + rl) * 128 + q * 8;

  f32x4 acc1[8] = {};
  #pragma unroll
  for (int ks = 0; ks < 4; ++ks) {
    u16x8 aF = *(const u16x8*)(zb + ks * 32);
    #pragma unroll
    for (int ct = 0; ct < 8; ++ct) {
      u16x8 bF = *(const u16x8*)(Wc1 + ((size_t)h * 128 + ct * 16 + rl) * 128 + ks * 32 + q * 8);
      acc1[ct] = mfma_bf16(aF, bF, acc1[ct]);
    }
  }

  #pragma unroll
  for (int j = 0; j < 4; ++j) {
    const int row = q * 4 + j;
    const int gr = r0 + row;
    const float den = dnm[((size_t)h * 4 + b) * N_ + (gr & 2047)];
    #pragma unroll
    for (int ct = 0; ct < 4; ++ct) {
      const int c = ct * 16 + rl;
      float g = (acc1[ct][j] + 2.f * bias0[h * 64 + c]) / den;
      unsigned short gb = f2bf(fmaxf(g, 0.f));
      g0s[w][row][c] = gb;
      G[(size_t)gr * 640 + h * 64 + c] = gb;
    }
  }
  __syncthreads();

  f32x4 acc2[4] = {};
  #pragma unroll
  for (int ks = 0; ks < 2; ++ks) {
    u16x8 aF = *(const u16x8*)&g0s[w][rl][ks * 32 + q * 8];
    #pragma unroll
    for (int ct = 0; ct < 4; ++ct) {
      u16x8 bF = *(const u16x8*)(Wc2 + ((size_t)h * 64 + ct * 16 + rl) * 64 + ks * 32 + q * 8);
      acc2[ct] = mfma_bf16(aF, bF, acc2[ct]);
    }
  }

  #pragma unroll
  for (int j = 0; j < 4; ++j) {
    const int row = q * 4 + j;
    const int gr = r0 + row;
    #pragma unroll
    for (int ct = 0; ct < 4; ++ct) {
      const int c = ct * 16 + rl;
      float h0v = acc2[ct][j];
      float ev = acc1[4 + ct][j] + h0v + 2.f * bias1[h * 64 + c];
      e_b[((size_t)h * 8192 + gr) * 64 + c] = f2bf(ev);
      h0s[w][row][c] = f2bf(h0v);
    }
  }
  __syncthreads();

  {
    u16x8 t0, t1;
    #pragma unroll
    for (int r = 0; r < 8; ++r) t0[r] = h0s[w][r][lane];
    #pragma unroll
    for (int r = 0; r < 8; ++r) t1[r] = h0s[w][8 + r][lane];
    unsigned short* dst = h0T + (((size_t)h * 4 + b) * 64 + lane) * N_ + n0 + w * 16;
    *(u16x8*)dst = t0;
    *(u16x8*)(dst + 8) = t1;
  }
}

// ---------------- pass2: g1 = relu((adjb@h0 + e)/den) ----------------
// 32 rows x 64 cols per block, 4 waves 2x2. A and B gl_lds-staged, dbuf.
__global__ __launch_bounds__(256, 3) void pass2_kernel(
    const unsigned short* __restrict__ adjb, const unsigned short* __restrict__ h0T,
    const unsigned short* __restrict__ e_b, const float* __restrict__ dnm,
    unsigned short* __restrict__ G)
{
  const int tid = threadIdx.x, lane = tid & 63, w = tid >> 6;
  const int wr = w >> 1, wc = w & 1;
  const int rl = lane & 15, q = lane >> 4;
  const int bh = blockIdx.y, b = bh >> 2, h = bh & 3, hb = h * 4 + b;
  const int row0 = blockIdx.x * 32;

  __shared__ __align__(16) unsigned short At[2][32 * 128];   // 2 x 8 KB
  __shared__ __align__(16) unsigned short Bt[2][64 * 128];   // 2 x 16 KB

  const int r4 = lane >> 4;
  const int cb = (lane & 15) * 16;
  const int e0 = (cb ^ (r4 << 4)) >> 1;
  const int e1 = (cb ^ ((4 + r4) << 4)) >> 1;
  const unsigned short* hbse = h0T + (size_t)hb * 64 * N_;
  const unsigned short* ab = adjb + ((size_t)bh * N_ + row0) * N_;

  const int swz = (rl & 7) << 4;
  const int ra = wr * 16 + rl;
  const int raswz = (ra & 7) << 4;

  f32x4 acc[2] = {};

  auto stage = [&](int buf, int kb) {
    #pragma unroll
    for (int i = 0; i < 2; ++i) {   // A rows w*8 + i*4 + r4
      const int R0 = w * 8 + i * 4;
      gl_lds16(ab + (size_t)(R0 + r4) * N_ + kb * 128 + ((i & 1) ? e1 : e0),
               &At[buf][R0 * 128]);
    }
    #pragma unroll
    for (int i = 0; i < 4; ++i) {   // B rows w*16 + i*4 + r4
      const int R0 = w * 16 + i * 4;
      gl_lds16(hbse + (size_t)(R0 + r4) * N_ + kb * 128 + ((i & 1) ? e1 : e0),
               &Bt[buf][R0 * 128]);
    }
  };

  stage(0, 0);
  __syncthreads();

  for (int kb = 0; kb < 16; ++kb) {
    const int cur = kb & 1;
    if (kb < 15) stage(cur ^ 1, kb + 1);
    #pragma unroll
    for (int ks = 0; ks < 4; ++ks) {
      u16x8 aF = *(const u16x8*)((const char*)&At[cur][0] + ra * 256 +
                                 ((ks * 64 + q * 16) ^ raswz));
      #pragma unroll
      for (int ct = 0; ct < 2; ++ct) {
        const int R = wc * 32 + ct * 16 + rl;
        u16x8 bF = *(const u16x8*)((const char*)&Bt[cur][0] + R * 256 +
                                   ((ks * 64 + q * 16) ^ swz));
        acc[ct] = mfma_bf16(aF, bF, acc[ct]);
      }
    }
    __syncthreads();
  }

  #pragma unroll
  for (int j = 0; j < 4; ++j) {
    const int n = row0 + wr * 16 + q * 4 + j;
    const float den = dnm[(size_t)hb * N_ + n];
    const unsigned short* er = e_b + ((size_t)hb * N_ + n) * 64;
    unsigned short* gr = G + ((size_t)b * N_ + n) * 640 + 256 + h * 64;
    #pragma unroll
    for (int ct = 0; ct < 2; ++ct) {
      const int c = wc * 32 + ct * 16 + rl;
      float v = (acc[ct][j] + bf2f(er[c])) / den;
      gr[c] = f2bf(fmaxf(v, 0.f));
    }
  }
}

// ---------------- pass3: out = G @ Wcat^T + bf ----------------
__global__ __launch_bounds__(256) void pass3_kernel(
    const unsigned short* __restrict__ G, const unsigned short* __restrict__ Wcat,
    const float* __restrict__ bfv, float* __restrict__ out)
{
  const int tid = threadIdx.x, lane = tid & 63, w = tid >> 6;
  const int wc = w & 1, kc = w >> 1, rl = lane & 15, q = lane >> 4;
  const int row0 = blockIdx.x * 16;   // over B*N = 8192

  __shared__ float red[2][16][68];

  const unsigned short* aP = G + (size_t)(row0 + rl) * 640 + kc * 320 + q * 8;
  const unsigned short* wP = Wcat + (size_t)kc * 320 + q * 8;

  f32x4 acc[4] = {};
  #pragma unroll
  for (int t = 0; t < 10; ++t) {
    u16x8 aF = *(const u16x8*)(aP + (size_t)t * 32);
    #pragma unroll
    for (int ct = 0; ct < 4; ++ct) {
      u16x8 bF = *(const u16x8*)(wP + (size_t)(wc * 64 + ct * 16 + rl) * 640 + t * 32);
      acc[ct] = mfma_bf16(aF, bF, acc[ct]);
    }
  }

  if (kc == 1) {
    #pragma unroll
    for (int j = 0; j < 4; ++j)
      #pragma unroll
      for (int ct = 0; ct < 4; ++ct)
        red[wc][q * 4 + j][ct * 16 + rl] = acc[ct][j];
  }
  __syncthreads();
  if (kc == 0) {
    #pragma unroll
    for (int j = 0; j < 4; ++j) {
      const int row = q * 4 + j;
      float* orow = out + (size_t)(row0 + row) * 128;
      #pragma unroll
      for (int ct = 0; ct < 4; ++ct) {
        const int c = wc * 64 + ct * 16 + rl;
        orow[c] = acc[ct][j] + red[wc][row][ct * 16 + rl] + bfv[c];
      }
    }
  }
}

// ---------------- launch ----------------
extern "C" void kernel_launch(void* const* d_in, const int* in_sizes, int n_in,
                              void* d_out, int out_size, void* d_ws, size_t ws_size,
                              hipStream_t stream) {
  const float* adj = (const float*)d_in[0];
  const float* X   = (const float*)d_in[1];
  const float* w0  = (const float*)d_in[2];
  const float* b0  = (const float*)d_in[3];
  const float* w1  = (const float*)d_in[4];
  const float* b1  = (const float*)d_in[5];
  const float* Wf  = (const float*)d_in[6];
  const float* bf  = (const float*)d_in[7];
  float* out = (float*)d_out;
  char* ws = (char*)d_ws;

  unsigned short* XbT  = (unsigned short*)(ws + 0);          //  2,097,152
  unsigned short* Wc1  = (unsigned short*)(ws + 2097152);    //    131,072
  unsigned short* Wc2  = (unsigned short*)(ws + 2228224);    //     32,768
  unsigned short* Wcat = (unsigned short*)(ws + 2260992);    //    163,840
  unsigned short* Z0b  = (unsigned short*)(ws + 2424832);    //  8,388,608
  float*          dnm  = (float*)(ws + 10813440);            //    131,072
  unsigned short* e_b  = (unsigned short*)(ws + 10944512);   //  4,194,304
  unsigned short* h0T  = (unsigned short*)(ws + 15138816);   //  4,194,304
  unsigned short* G    = (unsigned short*)(ws + 19333120);   // 10,485,760
  unsigned short* adjb = (unsigned short*)(ws + 33554432);   // 134,217,728 (end 160 MB)

  hipLaunchKernelGGL(prep_weights, dim3(640), dim3(256), 0, stream, w0, w1, Wf, Wc1, Wc2, Wcat);
  hipLaunchKernelGGL(prep_x,       dim3(128), dim3(256), 0, stream, X, XbT, G);
  hipLaunchKernelGGL(conv_adj,     dim3(8192), dim3(256), 0, stream, adj, adjb, dnm);
  hipLaunchKernelGGL(pass1_kernel, dim3(64, 16), dim3(256), 0, stream, adjb, X, XbT, Z0b);
  hipLaunchKernelGGL(mid_kernel,   dim3(128, 4), dim3(256), 0, stream, Z0b, dnm, Wc1, Wc2, b0, b1, e_b, h0T, G);
  hipLaunchKernelGGL(pass2_kernel, dim3(64, 16), dim3(256), 0, stream, adjb, h0T, e_b, dnm, G);
  hipLaunchKernelGGL(pass3_kernel, dim3(512), dim3(256), 0, stream, G, Wcat, bf, out);
}

// Round 9
// 190.368 us; speedup vs baseline: 1.3434x; 1.3434x over previous
//
#include <hip/hip_runtime.h>

#define N_ 2048

typedef __attribute__((ext_vector_type(8))) __bf16 bf16x8;
typedef __attribute__((ext_vector_type(8))) unsigned short u16x8;
typedef __attribute__((ext_vector_type(4))) unsigned short u16x4;
typedef __attribute__((ext_vector_type(4))) float f32x4;

#define WAIT_VM(Nlit) asm volatile("s_waitcnt vmcnt(" #Nlit ")" ::: "memory")
#define WAIT_LGKM     asm volatile("s_waitcnt lgkmcnt(0)" ::: "memory")
#define SCHED_B       __builtin_amdgcn_sched_barrier(0)
#define S_BAR         __builtin_amdgcn_s_barrier()

__device__ inline unsigned short f2bf(float f) {
  return __builtin_bit_cast(unsigned short, static_cast<__bf16>(f));
}
__device__ inline float bf2f(unsigned short s) {
  unsigned u = ((unsigned)s) << 16;
  return __builtin_bit_cast(float, u);
}

__device__ inline f32x4 mfma_bf16(u16x8 a, u16x8 b, f32x4 c) {
  return __builtin_amdgcn_mfma_f32_16x16x32_bf16(
      __builtin_bit_cast(bf16x8, a), __builtin_bit_cast(bf16x8, b), c, 0, 0, 0);
}

// async global->LDS, 16B per lane, linear LDS dest (wave-uniform base + lane*16)
__device__ __forceinline__ void gl_lds16(const unsigned short* g, unsigned short* l) {
  __builtin_amdgcn_global_load_lds(
      (const __attribute__((address_space(1))) unsigned int*)g,
      (__attribute__((address_space(3))) unsigned int*)l, 16, 0, 0);
}

// ---------------- prep: pack weights to bf16 ----------------
__global__ __launch_bounds__(256) void prep_weights(
    const float* __restrict__ w0, const float* __restrict__ w1,
    const float* __restrict__ Wf,
    unsigned short* __restrict__ Wc1, unsigned short* __restrict__ Wc2,
    unsigned short* __restrict__ Wcat)
{
  int idx = blockIdx.x * 256 + threadIdx.x;
  if (idx < 65536) {
    int h = idx >> 14, r = (idx >> 7) & 127, k = idx & 127;
    float v = (r < 64) ? w0[(h * 64 + r) * 128 + k]
                       : w1[(h * 64 + (r - 64)) * 192 + k];
    Wc1[idx] = f2bf(v);
  } else if (idx < 81920) {
    int i = idx - 65536;
    int h = i >> 12, r = (i >> 6) & 63, k = i & 63;
    Wc2[i] = f2bf(w1[(h * 64 + r) * 192 + 128 + k]);
  } else if (idx < 163840) {
    int i = idx - 81920;
    int d = i / 640, c = i % 640;
    float v;
    if (c < 256)      { int h = c >> 6, j = c & 63;        v = Wf[d * 512 + h * 128 + j]; }
    else if (c < 512) { int h = (c - 256) >> 6, j = (c - 256) & 63; v = Wf[d * 512 + h * 128 + 64 + j]; }
    else {
      int k = c - 512; v = 0.f;
      for (int hh = 0; hh < 4; ++hh) v += Wf[d * 512 + hh * 128 + k];
    }
    Wcat[i] = f2bf(v);
  }
}

// ---------------- prep: X -> XbT (bf16 transpose [B][128][N]) + G X-slice ----------------
__global__ __launch_bounds__(256) void prep_x(
    const float* __restrict__ X, unsigned short* __restrict__ XbT,
    unsigned short* __restrict__ G)
{
  const int tid = threadIdx.x;
  const int b = blockIdx.x >> 5;
  const int n0 = (blockIdx.x & 31) * 64;
  __shared__ float tf[64][129];
  #pragma unroll
  for (int i = 0; i < 32; ++i) {
    int e = i * 256 + tid;          // 64x128 tile
    int nl = e >> 7, c = e & 127;
    float v = X[((size_t)b * N_ + n0 + nl) * 128 + c];
    tf[nl][c] = v;
    G[((size_t)b * N_ + n0 + nl) * 640 + 512 + c] = f2bf(v);
  }
  __syncthreads();
  #pragma unroll
  for (int i = 0; i < 32; ++i) {
    int e = i * 256 + tid;
    int c = e >> 6, nl = e & 63;
    XbT[((size_t)b * 128 + c) * N_ + n0 + nl] = f2bf(tf[nl][c]);
  }
}

// ---------------- conv_adj: adj fp32 -> adjb bf16, row-sums -> dnm ----------------
__global__ __launch_bounds__(256) void conv_adj(
    const float* __restrict__ adj, unsigned short* __restrict__ adjb,
    float* __restrict__ dnm)
{
  const int tid = threadIdx.x, lane = tid & 63, w = tid >> 6;
  const int gid = blockIdx.x * 4 + w;          // row over 16*2048
  const int bh = gid >> 11, r = gid & 2047;
  const float* src = adj + (size_t)gid * N_;
  unsigned short* dst = adjb + (size_t)gid * N_;
  float s = 0.f;
  #pragma unroll
  for (int j = 0; j < 8; ++j) {
    float4 v = *(const float4*)(src + j * 256 + lane * 4);
    s += (v.x + v.y) + (v.z + v.w);
    u16x4 o;
    o[0] = f2bf(v.x); o[1] = f2bf(v.y); o[2] = f2bf(v.z); o[3] = f2bf(v.w);
    *(u16x4*)(dst + j * 256 + lane * 4) = o;
  }
  s += __shfl_xor(s, 1, 64);
  s += __shfl_xor(s, 2, 64);
  s += __shfl_xor(s, 4, 64);
  s += __shfl_xor(s, 8, 64);
  s += __shfl_xor(s, 16, 64);
  s += __shfl_xor(s, 32, 64);
  if (lane == 0) {
    const int hb = (bh & 3) * 4 + (bh >> 2);
    dnm[(size_t)hb * N_ + r] = s + 1.0f;
  }
}

// ---------------- pass1: Z0 = adjb@X + X (bf16) ----------------
// 64 rows x 128 cols per block, 4 waves 2x2 (32r x 64c). K chunks of 64 (32 chunks).
// A+B via gl_lds, double-buffered, counted vmcnt (never drained in loop).
__global__ __launch_bounds__(256, 2) void pass1_kernel(
    const unsigned short* __restrict__ adjb, const float* __restrict__ X,
    const unsigned short* __restrict__ XbT,
    unsigned short* __restrict__ Z0b)
{
  const int tid = threadIdx.x, lane = tid & 63, w = tid >> 6;
  const int wr = w >> 1, wc = w & 1;
  const int rl = lane & 15, q = lane >> 4;
  const int bh = blockIdx.y, b = bh >> 2, h = bh & 3, hb = h * 4 + b;
  const int row0 = blockIdx.x * 64;

  __shared__ __align__(16) unsigned short At[2][64 * 64];    // 2 x 8 KB, rows 128 B
  __shared__ __align__(16) unsigned short Bt[2][128 * 64];   // 2 x 16 KB

  // stage mapping: 8 rows / instruction; lane -> row r8=lane>>3, slot s=lane&7
  const int r8 = lane >> 3, s = lane & 7;
  const int es = (s ^ r8) * 8;                 // swizzled source elem offset
  const unsigned short* ab = adjb + ((size_t)bh * N_ + row0) * N_;
  const unsigned short* xb = XbT + (size_t)b * 128 * N_;

  f32x4 acc[2][4] = {};

  auto stage = [&](int buf, int kb) {
    #pragma unroll
    for (int j = 0; j < 2; ++j) {              // A: 2 insts/wave (8 total)
      const int R0 = (w * 2 + j) * 8;
      gl_lds16(ab + (size_t)(R0 + r8) * N_ + kb * 64 + es, &At[buf][R0 * 64]);
    }
    #pragma unroll
    for (int j = 0; j < 4; ++j) {              // B: 4 insts/wave (16 total)
      const int R0 = (w * 4 + j) * 8;
      gl_lds16(xb + (size_t)(R0 + r8) * N_ + kb * 64 + es, &Bt[buf][R0 * 64]);
    }
  };
  auto compute = [&](int cur) {
    #pragma unroll
    for (int ks = 0; ks < 2; ++ks) {
      u16x8 a0, a1;
      {
        const int R = wr * 32 + rl;
        a0 = *(const u16x8*)&At[cur][R * 64 + (((ks * 4 + q) ^ (R & 7)) * 8)];
      }
      {
        const int R = wr * 32 + 16 + rl;
        a1 = *(const u16x8*)&At[cur][R * 64 + (((ks * 4 + q) ^ (R & 7)) * 8)];
      }
      #pragma unroll
      for (int ct = 0; ct < 4; ++ct) {
        const int C = wc * 64 + ct * 16 + rl;
        u16x8 bF = *(const u16x8*)&Bt[cur][C * 64 + (((ks * 4 + q) ^ (C & 7)) * 8)];
        acc[0][ct] = mfma_bf16(a0, bF, acc[0][ct]);
        acc[1][ct] = mfma_bf16(a1, bF, acc[1][ct]);
      }
    }
  };

  stage(0, 0);
  int cur = 0;
  for (int kb = 0; kb < 31; ++kb) {
    stage(cur ^ 1, kb + 1);
    WAIT_VM(6);  SCHED_B;   // chunk kb landed; kb+1's 6 loads stay in flight
    S_BAR;       SCHED_B;
    compute(cur);
    WAIT_LGKM;   SCHED_B;   // all waves done reading buf cur
    S_BAR;       SCHED_B;
    cur ^= 1;
  }
  WAIT_VM(0);  SCHED_B;
  S_BAR;       SCHED_B;
  compute(cur);

  #pragma unroll
  for (int rt = 0; rt < 2; ++rt) {
    #pragma unroll
    for (int j = 0; j < 4; ++j) {
      const int n = row0 + wr * 32 + rt * 16 + q * 4 + j;
      const float* xr = X + ((size_t)b * N_ + n) * 128;
      unsigned short* zr = Z0b + ((size_t)hb * N_ + n) * 128;
      #pragma unroll
      for (int ct = 0; ct < 4; ++ct) {
        const int c = wc * 64 + ct * 16 + rl;
        zr[c] = f2bf(acc[rt][ct][j] + xr[c]);
      }
    }
  }
}

// ---------------- mid: g0, h0 = g0@w1b^T, e = Z0@w1a^T + h0 + 2*b1 ----------------
__global__ __launch_bounds__(256) void mid_kernel(
    const unsigned short* __restrict__ Z0b, const float* __restrict__ dnm,
    const unsigned short* __restrict__ Wc1, const unsigned short* __restrict__ Wc2,
    const float* __restrict__ bias0, const float* __restrict__ bias1,
    unsigned short* __restrict__ e_b, unsigned short* __restrict__ h0T,
    unsigned short* __restrict__ G)
{
  const int tid = threadIdx.x, lane = tid & 63, w = tid >> 6;
  const int rl = lane & 15, q = lane >> 4;
  const int h = blockIdx.y;
  const int rowbase = blockIdx.x * 64;      // over B*N = 8192
  const int b = rowbase >> 11, n0 = rowbase & 2047;
  const int r0 = rowbase + w * 16;

  __shared__ unsigned short g0s[4][16][72];
  __shared__ unsigned short h0s[4][16][72];

  const unsigned short* zb = Z0b + ((size_t)h * 8192 + r0 + rl) * 128 + q * 8;

  f32x4 acc1[8] = {};
  #pragma unroll
  for (int ks = 0; ks < 4; ++ks) {
    u16x8 aF = *(const u16x8*)(zb + ks * 32);
    #pragma unroll
    for (int ct = 0; ct < 8; ++ct) {
      u16x8 bF = *(const u16x8*)(Wc1 + ((size_t)h * 128 + ct * 16 + rl) * 128 + ks * 32 + q * 8);
      acc1[ct] = mfma_bf16(aF, bF, acc1[ct]);
    }
  }

  #pragma unroll
  for (int j = 0; j < 4; ++j) {
    const int row = q * 4 + j;
    const int gr = r0 + row;
    const float den = dnm[((size_t)h * 4 + b) * N_ + (gr & 2047)];
    #pragma unroll
    for (int ct = 0; ct < 4; ++ct) {
      const int c = ct * 16 + rl;
      float g = (acc1[ct][j] + 2.f * bias0[h * 64 + c]) / den;
      unsigned short gb = f2bf(fmaxf(g, 0.f));
      g0s[w][row][c] = gb;
      G[(size_t)gr * 640 + h * 64 + c] = gb;
    }
  }
  __syncthreads();

  f32x4 acc2[4] = {};
  #pragma unroll
  for (int ks = 0; ks < 2; ++ks) {
    u16x8 aF = *(const u16x8*)&g0s[w][rl][ks * 32 + q * 8];
    #pragma unroll
    for (int ct = 0; ct < 4; ++ct) {
      u16x8 bF = *(const u16x8*)(Wc2 + ((size_t)h * 64 + ct * 16 + rl) * 64 + ks * 32 + q * 8);
      acc2[ct] = mfma_bf16(aF, bF, acc2[ct]);
    }
  }

  #pragma unroll
  for (int j = 0; j < 4; ++j) {
    const int row = q * 4 + j;
    const int gr = r0 + row;
    #pragma unroll
    for (int ct = 0; ct < 4; ++ct) {
      const int c = ct * 16 + rl;
      float h0v = acc2[ct][j];
      float ev = acc1[4 + ct][j] + h0v + 2.f * bias1[h * 64 + c];
      e_b[((size_t)h * 8192 + gr) * 64 + c] = f2bf(ev);
      h0s[w][row][c] = f2bf(h0v);
    }
  }
  __syncthreads();

  {
    u16x8 t0, t1;
    #pragma unroll
    for (int r = 0; r < 8; ++r) t0[r] = h0s[w][r][lane];
    #pragma unroll
    for (int r = 0; r < 8; ++r) t1[r] = h0s[w][8 + r][lane];
    unsigned short* dst = h0T + (((size_t)h * 4 + b) * 64 + lane) * N_ + n0 + w * 16;
    *(u16x8*)dst = t0;
    *(u16x8*)(dst + 8) = t1;
  }
}

// ---------------- pass2: g1 = relu((adjb@h0 + e)/den) ----------------
// 64 rows x 64 cols per block, 4 waves 2x2 (32r x 32c). Same counted-vmcnt pipeline.
__global__ __launch_bounds__(256, 2) void pass2_kernel(
    const unsigned short* __restrict__ adjb, const unsigned short* __restrict__ h0T,
    const unsigned short* __restrict__ e_b, const float* __restrict__ dnm,
    unsigned short* __restrict__ G)
{
  const int tid = threadIdx.x, lane = tid & 63, w = tid >> 6;
  const int wr = w >> 1, wc = w & 1;
  const int rl = lane & 15, q = lane >> 4;
  const int bh = blockIdx.y, b = bh >> 2, h = bh & 3, hb = h * 4 + b;
  const int row0 = blockIdx.x * 64;

  __shared__ __align__(16) unsigned short At[2][64 * 64];   // 2 x 8 KB
  __shared__ __align__(16) unsigned short Bt[2][64 * 64];   // 2 x 8 KB

  const int r8 = lane >> 3, s = lane & 7;
  const int es = (s ^ r8) * 8;
  const unsigned short* ab = adjb + ((size_t)bh * N_ + row0) * N_;
  const unsigned short* hbse = h0T + (size_t)hb * 64 * N_;

  f32x4 acc[2][2] = {};

  auto stage = [&](int buf, int kb) {
    #pragma unroll
    for (int j = 0; j < 2; ++j) {              // A: 2 insts/wave
      const int R0 = (w * 2 + j) * 8;
      gl_lds16(ab + (size_t)(R0 + r8) * N_ + kb * 64 + es, &At[buf][R0 * 64]);
    }
    #pragma unroll
    for (int j = 0; j < 2; ++j) {              // B: 2 insts/wave
      const int R0 = (w * 2 + j) * 8;
      gl_lds16(hbse + (size_t)(R0 + r8) * N_ + kb * 64 + es, &Bt[buf][R0 * 64]);
    }
  };
  auto compute = [&](int cur) {
    #pragma unroll
    for (int ks = 0; ks < 2; ++ks) {
      u16x8 a0, a1;
      {
        const int R = wr * 32 + rl;
        a0 = *(const u16x8*)&At[cur][R * 64 + (((ks * 4 + q) ^ (R & 7)) * 8)];
      }
      {
        const int R = wr * 32 + 16 + rl;
        a1 = *(const u16x8*)&At[cur][R * 64 + (((ks * 4 + q) ^ (R & 7)) * 8)];
      }
      #pragma unroll
      for (int ct = 0; ct < 2; ++ct) {
        const int C = wc * 32 + ct * 16 + rl;
        u16x8 bF = *(const u16x8*)&Bt[cur][C * 64 + (((ks * 4 + q) ^ (C & 7)) * 8)];
        acc[0][ct] = mfma_bf16(a0, bF, acc[0][ct]);
        acc[1][ct] = mfma_bf16(a1, bF, acc[1][ct]);
      }
    }
  };

  stage(0, 0);
  int cur = 0;
  for (int kb = 0; kb < 31; ++kb) {
    stage(cur ^ 1, kb + 1);
    WAIT_VM(4);  SCHED_B;
    S_BAR;       SCHED_B;
    compute(cur);
    WAIT_LGKM;   SCHED_B;
    S_BAR;       SCHED_B;
    cur ^= 1;
  }
  WAIT_VM(0);  SCHED_B;
  S_BAR;       SCHED_B;
  compute(cur);

  #pragma unroll
  for (int rt = 0; rt < 2; ++rt) {
    #pragma unroll
    for (int j = 0; j < 4; ++j) {
      const int n = row0 + wr * 32 + rt * 16 + q * 4 + j;
      const float den = dnm[(size_t)hb * N_ + n];
      const unsigned short* er = e_b + ((size_t)hb * N_ + n) * 64;
      unsigned short* gr = G + ((size_t)b * N_ + n) * 640 + 256 + h * 64;
      #pragma unroll
      for (int ct = 0; ct < 2; ++ct) {
        const int c = wc * 32 + ct * 16 + rl;
        float v = (acc[rt][ct][j] + bf2f(er[c])) / den;
        gr[c] = f2bf(fmaxf(v, 0.f));
      }
    }
  }
}

// ---------------- pass3: out = G @ Wcat^T + bf ----------------
__global__ __launch_bounds__(256) void pass3_kernel(
    const unsigned short* __restrict__ G, const unsigned short* __restrict__ Wcat,
    const float* __restrict__ bfv, float* __restrict__ out)
{
  const int tid = threadIdx.x, lane = tid & 63, w = tid >> 6;
  const int wc = w & 1, kc = w >> 1, rl = lane & 15, q = lane >> 4;
  const int row0 = blockIdx.x * 16;   // over B*N = 8192

  __shared__ float red[2][16][68];

  const unsigned short* aP = G + (size_t)(row0 + rl) * 640 + kc * 320 + q * 8;
  const unsigned short* wP = Wcat + (size_t)kc * 320 + q * 8;

  f32x4 acc[4] = {};
  #pragma unroll
  for (int t = 0; t < 10; ++t) {
    u16x8 aF = *(const u16x8*)(aP + (size_t)t * 32);
    #pragma unroll
    for (int ct = 0; ct < 4; ++ct) {
      u16x8 bF = *(const u16x8*)(wP + (size_t)(wc * 64 + ct * 16 + rl) * 640 + t * 32);
      acc[ct] = mfma_bf16(aF, bF, acc[ct]);
    }
  }

  if (kc == 1) {
    #pragma unroll
    for (int j = 0; j < 4; ++j)
      #pragma unroll
      for (int ct = 0; ct < 4; ++ct)
        red[wc][q * 4 + j][ct * 16 + rl] = acc[ct][j];
  }
  __syncthreads();
  if (kc == 0) {
    #pragma unroll
    for (int j = 0; j < 4; ++j) {
      const int row = q * 4 + j;
      float* orow = out + (size_t)(row0 + row) * 128;
      #pragma unroll
      for (int ct = 0; ct < 4; ++ct) {
        const int c = wc * 64 + ct * 16 + rl;
        orow[c] = acc[ct][j] + red[wc][row][ct * 16 + rl] + bfv[c];
      }
    }
  }
}

// ---------------- launch ----------------
extern "C" void kernel_launch(void* const* d_in, const int* in_sizes, int n_in,
                              void* d_out, int out_size, void* d_ws, size_t ws_size,
                              hipStream_t stream) {
  const float* adj = (const float*)d_in[0];
  const float* X   = (const float*)d_in[1];
  const float* w0  = (const float*)d_in[2];
  const float* b0  = (const float*)d_in[3];
  const float* w1  = (const float*)d_in[4];
  const float* b1  = (const float*)d_in[5];
  const float* Wf  = (const float*)d_in[6];
  const float* bf  = (const float*)d_in[7];
  float* out = (float*)d_out;
  char* ws = (char*)d_ws;

  unsigned short* XbT  = (unsigned short*)(ws + 0);          //  2,097,152
  unsigned short* Wc1  = (unsigned short*)(ws + 2097152);    //    131,072
  unsigned short* Wc2  = (unsigned short*)(ws + 2228224);    //     32,768
  unsigned short* Wcat = (unsigned short*)(ws + 2260992);    //    163,840
  unsigned short* Z0b  = (unsigned short*)(ws + 2424832);    //  8,388,608
  float*          dnm  = (float*)(ws + 10813440);            //    131,072
  unsigned short* e_b  = (unsigned short*)(ws + 10944512);   //  4,194,304
  unsigned short* h0T  = (unsigned short*)(ws + 15138816);   //  4,194,304
  unsigned short* G    = (unsigned short*)(ws + 19333120);   // 10,485,760
  unsigned short* adjb = (unsigned short*)(ws + 33554432);   // 134,217,728 (end 160 MB)

  hipLaunchKernelGGL(prep_weights, dim3(640), dim3(256), 0, stream, w0, w1, Wf, Wc1, Wc2, Wcat);
  hipLaunchKernelGGL(prep_x,       dim3(128), dim3(256), 0, stream, X, XbT, G);
  hipLaunchKernelGGL(conv_adj,     dim3(8192), dim3(256), 0, stream, adj, adjb, dnm);
  hipLaunchKernelGGL(pass1_kernel, dim3(32, 16), dim3(256), 0, stream, adjb, X, XbT, Z0b);
  hipLaunchKernelGGL(mid_kernel,   dim3(128, 4), dim3(256), 0, stream, Z0b, dnm, Wc1, Wc2, b0, b1, e_b, h0T, G);
  hipLaunchKernelGGL(pass2_kernel, dim3(32, 16), dim3(256), 0, stream, adjb, h0T, e_b, dnm, G);
  hipLaunchKernelGGL(pass3_kernel, dim3(512), dim3(256), 0, stream, G, Wcat, bf, out);
}

// Round 10
// 158.273 us; speedup vs baseline: 1.6158x; 1.2028x over previous
//
#include <hip/hip_runtime.h>

#define N_ 2048

typedef __attribute__((ext_vector_type(8))) __bf16 bf16x8;
typedef __attribute__((ext_vector_type(8))) unsigned short u16x8;
typedef __attribute__((ext_vector_type(4))) float f32x4;

#define WAIT_VM(Nlit) asm volatile("s_waitcnt vmcnt(" #Nlit ")" ::: "memory")
#define WAIT_LGKM     asm volatile("s_waitcnt lgkmcnt(0)" ::: "memory")
#define SCHED_B       __builtin_amdgcn_sched_barrier(0)
#define S_BAR         __builtin_amdgcn_s_barrier()

__device__ inline unsigned short f2bf(float f) {
  return __builtin_bit_cast(unsigned short, static_cast<__bf16>(f));
}
__device__ inline float bf2f(unsigned short s) {
  unsigned u = ((unsigned)s) << 16;
  return __builtin_bit_cast(float, u);
}

__device__ inline f32x4 mfma_bf16(u16x8 a, u16x8 b, f32x4 c) {
  return __builtin_amdgcn_mfma_f32_16x16x32_bf16(
      __builtin_bit_cast(bf16x8, a), __builtin_bit_cast(bf16x8, b), c, 0, 0, 0);
}

// async global->LDS, 16B per lane, linear LDS dest (wave-uniform base + lane*16)
__device__ __forceinline__ void gl_lds16(const void* g, void* l) {
  __builtin_amdgcn_global_load_lds(
      (const __attribute__((address_space(1))) unsigned int*)g,
      (__attribute__((address_space(3))) unsigned int*)l, 16, 0, 0);
}

// ---------------- prep: pack weights to bf16 ----------------
__global__ __launch_bounds__(256) void prep_weights(
    const float* __restrict__ w0, const float* __restrict__ w1,
    const float* __restrict__ Wf,
    unsigned short* __restrict__ Wc1, unsigned short* __restrict__ Wc2,
    unsigned short* __restrict__ Wcat)
{
  int idx = blockIdx.x * 256 + threadIdx.x;
  if (idx < 65536) {
    int h = idx >> 14, r = (idx >> 7) & 127, k = idx & 127;
    float v = (r < 64) ? w0[(h * 64 + r) * 128 + k]
                       : w1[(h * 64 + (r - 64)) * 192 + k];
    Wc1[idx] = f2bf(v);
  } else if (idx < 81920) {
    int i = idx - 65536;
    int h = i >> 12, r = (i >> 6) & 63, k = i & 63;
    Wc2[i] = f2bf(w1[(h * 64 + r) * 192 + 128 + k]);
  } else if (idx < 163840) {
    int i = idx - 81920;
    int d = i / 640, c = i % 640;
    float v;
    if (c < 256)      { int h = c >> 6, j = c & 63;        v = Wf[d * 512 + h * 128 + j]; }
    else if (c < 512) { int h = (c - 256) >> 6, j = (c - 256) & 63; v = Wf[d * 512 + h * 128 + 64 + j]; }
    else {
      int k = c - 512; v = 0.f;
      for (int hh = 0; hh < 4; ++hh) v += Wf[d * 512 + hh * 128 + k];
    }
    Wcat[i] = f2bf(v);
  }
}

// ---------------- prep: X -> XbT (bf16 transpose [B][128][N]) + G X-slice ----------------
__global__ __launch_bounds__(256) void prep_x(
    const float* __restrict__ X, unsigned short* __restrict__ XbT,
    unsigned short* __restrict__ G)
{
  const int tid = threadIdx.x;
  const int b = blockIdx.x >> 5;
  const int n0 = (blockIdx.x & 31) * 64;
  __shared__ float tf[64][129];
  #pragma unroll
  for (int i = 0; i < 32; ++i) {
    int e = i * 256 + tid;          // 64x128 tile
    int nl = e >> 7, c = e & 127;
    float v = X[((size_t)b * N_ + n0 + nl) * 128 + c];
    tf[nl][c] = v;
    G[((size_t)b * N_ + n0 + nl) * 640 + 512 + c] = f2bf(v);
  }
  __syncthreads();
  #pragma unroll
  for (int i = 0; i < 32; ++i) {
    int e = i * 256 + tid;
    int c = e >> 6, nl = e & 63;
    XbT[((size_t)b * 128 + c) * N_ + n0 + nl] = f2bf(tf[nl][c]);
  }
}

// ---------------- pass1: Z0 = adj@X + X (bf16), denom ----------------
// 64 rows x 128 cols per block, 4 waves 2x2 (32r x 64c). K chunks of 64 (32 chunks).
// A staged as fp32 via gl_lds (cvt in-register after LDS read, row-sums folded);
// B bf16 via gl_lds. Double-buffered, counted vmcnt (never drained in loop).
__global__ __launch_bounds__(256, 2) void pass1_kernel(
    const float* __restrict__ adj, const float* __restrict__ X,
    const unsigned short* __restrict__ XbT,
    unsigned short* __restrict__ Z0b, float* __restrict__ dnm)
{
  const int tid = threadIdx.x, lane = tid & 63, w = tid >> 6;
  const int wr = w >> 1, wc = w & 1;
  const int rl = lane & 15, q = lane >> 4;
  const int bh = blockIdx.y, b = bh >> 2, h = bh & 3, hb = h * 4 + b;
  const int row0 = blockIdx.x * 64;

  __shared__ __align__(16) float Af[2][64 * 64];             // 2 x 16 KB, rows 256 B
  __shared__ __align__(16) unsigned short Bt[2][128 * 64];   // 2 x 16 KB, rows 128 B

  // A staging: 4 rows/inst; lane -> row r4 = lane>>4, 16B-slot sA = lane&15
  const int r4 = lane >> 4, sA = lane & 15;
  // B staging: 8 rows/inst; lane -> row r8 = lane>>3, slot s8 = lane&7
  const int r8 = lane >> 3, s8 = lane & 7;
  const int esB = (s8 ^ r8) * 8;                  // bf16 elems, swizzled
  const float* arow = adj + ((size_t)bh * N_ + row0) * N_;
  const unsigned short* xb = XbT + (size_t)b * 128 * N_;

  f32x4 acc[2][4] = {};
  float rs0 = 0.f, rs1 = 0.f;

  auto stage = [&](int buf, int kb) {
    #pragma unroll
    for (int j = 0; j < 4; ++j) {   // A: rows w*16 + j*4 + r4  (4 insts/wave)
      const int R0 = w * 16 + j * 4;
      const int esA = (sA ^ ((j & 1) * 4 + r4)) * 4;   // fp32 elems, swizzled
      gl_lds16(arow + (size_t)(R0 + r4) * N_ + kb * 64 + esA, &Af[buf][R0 * 64]);
    }
    #pragma unroll
    for (int j = 0; j < 4; ++j) {   // B: rows (w*4+j)*8  (4 insts/wave)
      const int R0 = (w * 4 + j) * 8;
      gl_lds16(xb + (size_t)(R0 + r8) * N_ + kb * 64 + esB, &Bt[buf][R0 * 64]);
    }
  };
  auto compute = [&](int cur) {
    #pragma unroll
    for (int ks = 0; ks < 2; ++ks) {
      u16x8 aF[2];
      #pragma unroll
      for (int rt = 0; rt < 2; ++rt) {
        const int R = wr * 32 + rt * 16 + rl;
        const int m = R & 7;
        f32x4 f0 = *(const f32x4*)&Af[cur][R * 64 + (ks * 8 + ((q * 2) ^ m)) * 4];
        f32x4 f1 = *(const f32x4*)&Af[cur][R * 64 + (ks * 8 + ((q * 2 + 1) ^ m)) * 4];
        float sr = (f0.x + f0.y) + (f0.z + f0.w) + (f1.x + f1.y) + (f1.z + f1.w);
        if (rt == 0) rs0 += sr; else rs1 += sr;
        u16x8 v;
        v[0] = f2bf(f0.x); v[1] = f2bf(f0.y); v[2] = f2bf(f0.z); v[3] = f2bf(f0.w);
        v[4] = f2bf(f1.x); v[5] = f2bf(f1.y); v[6] = f2bf(f1.z); v[7] = f2bf(f1.w);
        aF[rt] = v;
      }
      #pragma unroll
      for (int ct = 0; ct < 4; ++ct) {
        const int C = wc * 64 + ct * 16 + rl;
        u16x8 bF = *(const u16x8*)&Bt[cur][C * 64 + (((ks * 4 + q) ^ (C & 7)) * 8)];
        acc[0][ct] = mfma_bf16(aF[0], bF, acc[0][ct]);
        acc[1][ct] = mfma_bf16(aF[1], bF, acc[1][ct]);
      }
    }
  };

  stage(0, 0);
  int cur = 0;
  for (int kb = 0; kb < 31; ++kb) {
    stage(cur ^ 1, kb + 1);
    WAIT_VM(8);  SCHED_B;   // chunk kb landed; kb+1's 8 loads stay in flight
    S_BAR;       SCHED_B;
    compute(cur);
    WAIT_LGKM;   SCHED_B;   // all waves done reading buf cur
    S_BAR;       SCHED_B;
    cur ^= 1;
  }
  WAIT_VM(0);  SCHED_B;
  S_BAR;       SCHED_B;
  compute(cur);

  // row-sums: each lane covers k ≡ [q*8, q*8+8) mod 32 over all chunks (x2 with wc dup).
  rs0 += __shfl_xor(rs0, 16, 64);
  rs0 += __shfl_xor(rs0, 32, 64);
  rs1 += __shfl_xor(rs1, 16, 64);
  rs1 += __shfl_xor(rs1, 32, 64);
  if (q == 0 && wc == 0) {
    dnm[(size_t)hb * N_ + row0 + wr * 32 + rl]      = rs0 + 1.0f;
    dnm[(size_t)hb * N_ + row0 + wr * 32 + 16 + rl] = rs1 + 1.0f;
  }

  #pragma unroll
  for (int rt = 0; rt < 2; ++rt) {
    #pragma unroll
    for (int j = 0; j < 4; ++j) {
      const int n = row0 + wr * 32 + rt * 16 + q * 4 + j;
      const float* xr = X + ((size_t)b * N_ + n) * 128;
      unsigned short* zr = Z0b + ((size_t)hb * N_ + n) * 128;
      #pragma unroll
      for (int ct = 0; ct < 4; ++ct) {
        const int c = wc * 64 + ct * 16 + rl;
        zr[c] = f2bf(acc[rt][ct][j] + xr[c]);
      }
    }
  }
}

// ---------------- mid: g0, h0 = g0@w1b^T, e = Z0@w1a^T + h0 + 2*b1 ----------------
__global__ __launch_bounds__(256) void mid_kernel(
    const unsigned short* __restrict__ Z0b, const float* __restrict__ dnm,
    const unsigned short* __restrict__ Wc1, const unsigned short* __restrict__ Wc2,
    const float* __restrict__ bias0, const float* __restrict__ bias1,
    unsigned short* __restrict__ e_b, unsigned short* __restrict__ h0T,
    unsigned short* __restrict__ G)
{
  const int tid = threadIdx.x, lane = tid & 63, w = tid >> 6;
  const int rl = lane & 15, q = lane >> 4;
  const int h = blockIdx.y;
  const int rowbase = blockIdx.x * 64;      // over B*N = 8192
  const int b = rowbase >> 11, n0 = rowbase & 2047;
  const int r0 = rowbase + w * 16;

  __shared__ unsigned short g0s[4][16][72];
  __shared__ unsigned short h0s[4][16][72];

  const unsigned short* zb = Z0b + ((size_t)h * 8192 + r0 + rl) * 128 + q * 8;

  f32x4 acc1[8] = {};
  #pragma unroll
  for (int ks = 0; ks < 4; ++ks) {
    u16x8 aF = *(const u16x8*)(zb + ks * 32);
    #pragma unroll
    for (int ct = 0; ct < 8; ++ct) {
      u16x8 bF = *(const u16x8*)(Wc1 + ((size_t)h * 128 + ct * 16 + rl) * 128 + ks * 32 + q * 8);
      acc1[ct] = mfma_bf16(aF, bF, acc1[ct]);
    }
  }

  #pragma unroll
  for (int j = 0; j < 4; ++j) {
    const int row = q * 4 + j;
    const int gr = r0 + row;
    const float den = dnm[((size_t)h * 4 + b) * N_ + (gr & 2047)];
    #pragma unroll
    for (int ct = 0; ct < 4; ++ct) {
      const int c = ct * 16 + rl;
      float g = (acc1[ct][j] + 2.f * bias0[h * 64 + c]) / den;
      unsigned short gb = f2bf(fmaxf(g, 0.f));
      g0s[w][row][c] = gb;
      G[(size_t)gr * 640 + h * 64 + c] = gb;
    }
  }
  __syncthreads();

  f32x4 acc2[4] = {};
  #pragma unroll
  for (int ks = 0; ks < 2; ++ks) {
    u16x8 aF = *(const u16x8*)&g0s[w][rl][ks * 32 + q * 8];
    #pragma unroll
    for (int ct = 0; ct < 4; ++ct) {
      u16x8 bF = *(const u16x8*)(Wc2 + ((size_t)h * 64 + ct * 16 + rl) * 64 + ks * 32 + q * 8);
      acc2[ct] = mfma_bf16(aF, bF, acc2[ct]);
    }
  }

  #pragma unroll
  for (int j = 0; j < 4; ++j) {
    const int row = q * 4 + j;
    const int gr = r0 + row;
    #pragma unroll
    for (int ct = 0; ct < 4; ++ct) {
      const int c = ct * 16 + rl;
      float h0v = acc2[ct][j];
      float ev = acc1[4 + ct][j] + h0v + 2.f * bias1[h * 64 + c];
      e_b[((size_t)h * 8192 + gr) * 64 + c] = f2bf(ev);
      h0s[w][row][c] = f2bf(h0v);
    }
  }
  __syncthreads();

  {
    u16x8 t0, t1;
    #pragma unroll
    for (int r = 0; r < 8; ++r) t0[r] = h0s[w][r][lane];
    #pragma unroll
    for (int r = 0; r < 8; ++r) t1[r] = h0s[w][8 + r][lane];
    unsigned short* dst = h0T + (((size_t)h * 4 + b) * 64 + lane) * N_ + n0 + w * 16;
    *(u16x8*)dst = t0;
    *(u16x8*)(dst + 8) = t1;
  }
}

// ---------------- pass2: g1 = relu((adj@h0 + e)/den) ----------------
// 64 rows x 64 cols per block, 4 waves 2x2 (32r x 32c). A fp32 via gl_lds + cvt.
__global__ __launch_bounds__(256, 3) void pass2_kernel(
    const float* __restrict__ adj, const unsigned short* __restrict__ h0T,
    const unsigned short* __restrict__ e_b, const float* __restrict__ dnm,
    unsigned short* __restrict__ G)
{
  const int tid = threadIdx.x, lane = tid & 63, w = tid >> 6;
  const int wr = w >> 1, wc = w & 1;
  const int rl = lane & 15, q = lane >> 4;
  const int bh = blockIdx.y, b = bh >> 2, h = bh & 3, hb = h * 4 + b;
  const int row0 = blockIdx.x * 64;

  __shared__ __align__(16) float Af[2][64 * 64];            // 2 x 16 KB
  __shared__ __align__(16) unsigned short Bt[2][64 * 64];   // 2 x 8 KB

  const int r4 = lane >> 4, sA = lane & 15;
  const int r8 = lane >> 3, s8 = lane & 7;
  const int esB = (s8 ^ r8) * 8;
  const float* arow = adj + ((size_t)bh * N_ + row0) * N_;
  const unsigned short* hbse = h0T + (size_t)hb * 64 * N_;

  f32x4 acc[2][2] = {};

  auto stage = [&](int buf, int kb) {
    #pragma unroll
    for (int j = 0; j < 4; ++j) {   // A: rows w*16 + j*4 + r4  (4 insts/wave)
      const int R0 = w * 16 + j * 4;
      const int esA = (sA ^ ((j & 1) * 4 + r4)) * 4;
      gl_lds16(arow + (size_t)(R0 + r4) * N_ + kb * 64 + esA, &Af[buf][R0 * 64]);
    }
    #pragma unroll
    for (int j = 0; j < 2; ++j) {   // B: rows (w*2+j)*8  (2 insts/wave)
      const int R0 = (w * 2 + j) * 8;
      gl_lds16(hbse + (size_t)(R0 + r8) * N_ + kb * 64 + esB, &Bt[buf][R0 * 64]);
    }
  };
  auto compute = [&](int cur) {
    #pragma unroll
    for (int ks = 0; ks < 2; ++ks) {
      u16x8 aF[2];
      #pragma unroll
      for (int rt = 0; rt < 2; ++rt) {
        const int R = wr * 32 + rt * 16 + rl;
        const int m = R & 7;
        f32x4 f0 = *(const f32x4*)&Af[cur][R * 64 + (ks * 8 + ((q * 2) ^ m)) * 4];
        f32x4 f1 = *(const f32x4*)&Af[cur][R * 64 + (ks * 8 + ((q * 2 + 1) ^ m)) * 4];
        u16x8 v;
        v[0] = f2bf(f0.x); v[1] = f2bf(f0.y); v[2] = f2bf(f0.z); v[3] = f2bf(f0.w);
        v[4] = f2bf(f1.x); v[5] = f2bf(f1.y); v[6] = f2bf(f1.z); v[7] = f2bf(f1.w);
        aF[rt] = v;
      }
      #pragma unroll
      for (int ct = 0; ct < 2; ++ct) {
        const int C = wc * 32 + ct * 16 + rl;
        u16x8 bF = *(const u16x8*)&Bt[cur][C * 64 + (((ks * 4 + q) ^ (C & 7)) * 8)];
        acc[0][ct] = mfma_bf16(aF[0], bF, acc[0][ct]);
        acc[1][ct] = mfma_bf16(aF[1], bF, acc[1][ct]);
      }
    }
  };

  stage(0, 0);
  int cur = 0;
  for (int kb = 0; kb < 31; ++kb) {
    stage(cur ^ 1, kb + 1);
    WAIT_VM(6);  SCHED_B;
    S_BAR;       SCHED_B;
    compute(cur);
    WAIT_LGKM;   SCHED_B;
    S_BAR;       SCHED_B;
    cur ^= 1;
  }
  WAIT_VM(0);  SCHED_B;
  S_BAR;       SCHED_B;
  compute(cur);

  #pragma unroll
  for (int rt = 0; rt < 2; ++rt) {
    #pragma unroll
    for (int j = 0; j < 4; ++j) {
      const int n = row0 + wr * 32 + rt * 16 + q * 4 + j;
      const float den = dnm[(size_t)hb * N_ + n];
      const unsigned short* er = e_b + ((size_t)hb * N_ + n) * 64;
      unsigned short* gr = G + ((size_t)b * N_ + n) * 640 + 256 + h * 64;
      #pragma unroll
      for (int ct = 0; ct < 2; ++ct) {
        const int c = wc * 32 + ct * 16 + rl;
        float v = (acc[rt][ct][j] + bf2f(er[c])) / den;
        gr[c] = f2bf(fmaxf(v, 0.f));
      }
    }
  }
}

// ---------------- pass3: out = G @ Wcat^T + bf ----------------
__global__ __launch_bounds__(256) void pass3_kernel(
    const unsigned short* __restrict__ G, const unsigned short* __restrict__ Wcat,
    const float* __restrict__ bfv, float* __restrict__ out)
{
  const int tid = threadIdx.x, lane = tid & 63, w = tid >> 6;
  const int wc = w & 1, kc = w >> 1, rl = lane & 15, q = lane >> 4;
  const int row0 = blockIdx.x * 16;   // over B*N = 8192

  __shared__ float red[2][16][68];

  const unsigned short* aP = G + (size_t)(row0 + rl) * 640 + kc * 320 + q * 8;
  const unsigned short* wP = Wcat + (size_t)kc * 320 + q * 8;

  f32x4 acc[4] = {};
  #pragma unroll
  for (int t = 0; t < 10; ++t) {
    u16x8 aF = *(const u16x8*)(aP + (size_t)t * 32);
    #pragma unroll
    for (int ct = 0; ct < 4; ++ct) {
      u16x8 bF = *(const u16x8*)(wP + (size_t)(wc * 64 + ct * 16 + rl) * 640 + t * 32);
      acc[ct] = mfma_bf16(aF, bF, acc[ct]);
    }
  }

  if (kc == 1) {
    #pragma unroll
    for (int j = 0; j < 4; ++j)
      #pragma unroll
      for (int ct = 0; ct < 4; ++ct)
        red[wc][q * 4 + j][ct * 16 + rl] = acc[ct][j];
  }
  __syncthreads();
  if (kc == 0) {
    #pragma unroll
    for (int j = 0; j < 4; ++j) {
      const int row = q * 4 + j;
      float* orow = out + (size_t)(row0 + row) * 128;
      #pragma unroll
      for (int ct = 0; ct < 4; ++ct) {
        const int c = wc * 64 + ct * 16 + rl;
        orow[c] = acc[ct][j] + red[wc][row][ct * 16 + rl] + bfv[c];
      }
    }
  }
}

// ---------------- launch ----------------
extern "C" void kernel_launch(void* const* d_in, const int* in_sizes, int n_in,
                              void* d_out, int out_size, void* d_ws, size_t ws_size,
                              hipStream_t stream) {
  const float* adj = (const float*)d_in[0];
  const float* X   = (const float*)d_in[1];
  const float* w0  = (const float*)d_in[2];
  const float* b0  = (const float*)d_in[3];
  const float* w1  = (const float*)d_in[4];
  const float* b1  = (const float*)d_in[5];
  const float* Wf  = (const float*)d_in[6];
  const float* bf  = (const float*)d_in[7];
  float* out = (float*)d_out;
  char* ws = (char*)d_ws;

  unsigned short* XbT  = (unsigned short*)(ws + 0);          //  2,097,152
  unsigned short* Wc1  = (unsigned short*)(ws + 2097152);    //    131,072
  unsigned short* Wc2  = (unsigned short*)(ws + 2228224);    //     32,768
  unsigned short* Wcat = (unsigned short*)(ws + 2260992);    //    163,840
  unsigned short* Z0b  = (unsigned short*)(ws + 2424832);    //  8,388,608
  float*          dnm  = (float*)(ws + 10813440);            //    131,072
  unsigned short* e_b  = (unsigned short*)(ws + 10944512);   //  4,194,304
  unsigned short* h0T  = (unsigned short*)(ws + 15138816);   //  4,194,304
  unsigned short* G    = (unsigned short*)(ws + 19333120);   // 10,485,760  (end ~29.8 MB)

  hipLaunchKernelGGL(prep_weights, dim3(640), dim3(256), 0, stream, w0, w1, Wf, Wc1, Wc2, Wcat);
  hipLaunchKernelGGL(prep_x,       dim3(128), dim3(256), 0, stream, X, XbT, G);
  hipLaunchKernelGGL(pass1_kernel, dim3(32, 16), dim3(256), 0, stream, adj, X, XbT, Z0b, dnm);
  hipLaunchKernelGGL(mid_kernel,   dim3(128, 4), dim3(256), 0, stream, Z0b, dnm, Wc1, Wc2, b0, b1, e_b, h0T, G);
  hipLaunchKernelGGL(pass2_kernel, dim3(32, 16), dim3(256), 0, stream, adj, h0T, e_b, dnm, G);
  hipLaunchKernelGGL(pass3_kernel, dim3(512), dim3(256), 0, stream, G, Wcat, bf, out);
}